// Round 8
// baseline (2230.375 us; speedup 1.0000x reference)
//
#include <hip/hip_runtime.h>

// ---------------------------------------------------------------------------
// XiRNN (peephole LSTM) on MI355X.  B=64, T=188, I=512, H=R=1024.
//   k_prep : fp32->bf16; W_rec split hi+lo; h0/c0 split hi+lo; BOTH state
//            slots initialized with gen-tag 3 (per-dword 2-bit in-band tags).
//   k_px   : px[t][gate][j][b] = x[b,t,:]·W_ih[gate*H+j,:] + bias (MFMA GEMM)
//   k_scan : persistent kernel, 256 blocks (1/CU), 4 batch-groups of 16 rows
//            x 64 CUs. W_hh/W_rec_hi register-resident; W_rec_lo in LDS.
//   History: R9 batched sc0sc1 gather (1156us) / R10 poll-flood FAIL /
//   R11 go_word (1140us) / R12 balanced waves (1163us) -> step pinned ~6.1us
//   = serial coherent-RT chain [drain+flag] [poll] [gather].
//   R13/R14 FAILED accuracy (~0.029 BOTH, despite R14's h-precision fix):
//   error was never tag noise — it was FALSE VALIDATION: (a) k_prep only
//   initialized slot 1, so zero-filled / previous-run slot 0 data validated
//   as gen 0/1 at t=1..3; (b) 1-bit gen (period 4) structurally aliases
//   prep/stale data at some step regardless of prep tag choice.
//   R15 fixes the protocol, keeps the (unmeasured) tag-sync perf idea:
//     - 2-bit generation gen(t) = (t>>1)&3, carried per DWORD: bit0 in the
//       LSB of the even-j bf16, bit1 in the LSB of the odd-j bf16. Sound
//       even if 16B memory ops tear (dwords are the atomic unit).
//     - prep tags BOTH slots of all 4 state arrays with gen 3 == gen(-1):
//       t=0 reads it as the legitimate initial state; it can never falsely
//       validate later (first possible collision t=7, by which time skew<=1
//       guarantees the slot was overwritten: all CUs >= t-1 when any is at t).
//     - Staleness reachable during a gather is only {t-1 fresh, t-3, prep}:
//       gen(t-1) != gen(t-3) mod 4, prep=3 handled above => validation sound.
//     - All tags exactly absorbable: h AND c stored hi+lo; lo computed from
//       the TAGGED hi (absorbs hi tags exactly); lo's own tag ~2^-17.
//   Consumer: 32-chunk validated gather, retry until every dword fresh.
//   Producer: no drain, no flag; epilogue packs via LDS, 16B sc0 sc1 stores.
// ---------------------------------------------------------------------------

#define T_N 188

// ws byte offsets (256-aligned). Total = 132,911,104 B (~126.8 MiB).
#define WS_PX     0UL           // ushort[188*4096*64]   = 98,566,144 B
#define WS_XB     98566144UL    // ushort[64*188*512]    = 12,320,768 B
#define WS_WIHB   110886912UL   // ushort[4096*512]      =  4,194,304 B
#define WS_WCOMB  115081216UL   // ushort[6144*1024]     = 12,582,912 B
#define WS_HST    127664128UL   // ushort[2][64][1024]   =    262,144 B  (h_hi)
#define WS_CST    127926272UL   // ushort[2][64][1024]   =    262,144 B  (c_hi)
#define WS_FLAGS  128188416UL   // int[1024] (unused by scan; prep zeroes)
#define WS_WRECLO 128192512UL   // ushort[2048*1024]     =  4,194,304 B
#define WS_CSTLO  132386816UL   // ushort[2][64][1024]   =    262,144 B  (c_lo)
#define WS_HSTLO  132648960UL   // ushort[2][64][1024]   =    262,144 B  (h_lo)

typedef __attribute__((ext_vector_type(8))) short short8;
typedef __attribute__((ext_vector_type(4))) float f4;

__device__ __forceinline__ float b2f(unsigned short u) {
    union { unsigned int i; float f; } v; v.i = ((unsigned int)u) << 16; return v.f;
}
__device__ __forceinline__ unsigned short f2b(float f) {
    unsigned int u = __float_as_uint(f);
    return (unsigned short)((u + 0x7FFFu + ((u >> 16) & 1u)) >> 16);
}
__device__ __forceinline__ float sigf(float x) { return 1.0f / (1.0f + __expf(-x)); }
__device__ __forceinline__ float tanh_(float x) {
    float e = __expf(2.0f * x); return 1.0f - 2.0f / (e + 1.0f);
}
#define MFMA(a, b, c) __builtin_amdgcn_mfma_f32_16x16x32_bf16((a), (b), (c), 0, 0, 0)

// 16B device-coherent load (bypass L1/L2). Result NOT tracked by compiler
// waitcnt logic — caller must s_waitcnt vmcnt(0) + sched_barrier(0) before use.
#define LD16(dst, addr) \
    asm volatile("global_load_dwordx4 %0, %1, off sc0 sc1" : "=&v"(dst) : "v"(addr))
// 16B device-coherent store.
#define ST16(addr, data) \
    asm volatile("global_store_dwordx4 %0, %1, off sc0 sc1" :: "v"(addr), "v"(data) : "memory")

// XOR a chunk's 4 dwords against the expected tag pattern; nonzero bits at
// 0x00010001 positions => at least one dword is not generation `pat`.
__device__ __forceinline__ unsigned int tagxor(short8 v, unsigned int pat) {
    union { short8 s; unsigned int d[4]; } u; u.s = v;
    return (u.d[0] ^ pat) | (u.d[1] ^ pat) | (u.d[2] ^ pat) | (u.d[3] ^ pat);
}

// 64-FMA ballast burst between gather retries (DVFS activity + retry spacing).
#define BAL64()                                                            \
    _Pragma("unroll")                                                      \
    for (int u_ = 0; u_ < 16; ++u_) {                                      \
        bl0 = __builtin_fmaf(bl0, 1.0000001f, 1e-7f);                      \
        bl1 = __builtin_fmaf(bl1, 1.0000001f, 2e-7f);                      \
        bl2 = __builtin_fmaf(bl2, 1.0000001f, 3e-7f);                      \
        bl3 = __builtin_fmaf(bl3, 1.0000001f, 4e-7f);                      \
    }

__device__ __forceinline__ f4 px_init(const unsigned short* px, int t, int gate, int jg, int brow) {
    unsigned long long pv =
        *(const unsigned long long*)(px + ((long)(t * 4 + gate) * 1024 + jg) * 64 + brow);
    f4 r;
    r[0] = b2f((unsigned short)pv);
    r[1] = b2f((unsigned short)(pv >> 16));
    r[2] = b2f((unsigned short)(pv >> 32));
    r[3] = b2f((unsigned short)(pv >> 48));
    return r;
}

// ---------------------------------------------------------------------------
__global__ void k_prep(const float* __restrict__ x, const float* __restrict__ h0,
                       const float* __restrict__ c0, const float* __restrict__ wih,
                       const float* __restrict__ whh, const float* __restrict__ wrec,
                       unsigned short* __restrict__ xb, unsigned short* __restrict__ wihb,
                       unsigned short* __restrict__ wcomb, unsigned short* __restrict__ hst,
                       unsigned short* __restrict__ cst, unsigned short* __restrict__ wreclo,
                       unsigned short* __restrict__ cstlo, unsigned short* __restrict__ hstlo,
                       int* __restrict__ flags) {
    const long NX4 = 1540096, NWIH4 = 524288, NWHH4 = 1048576, NWREC4 = 524288, NH4 = 16384;
    const long total = NX4 + NWIH4 + NWHH4 + NWREC4 + NH4 + NH4;
    long gtid = (long)blockIdx.x * blockDim.x + threadIdx.x;
    for (long i = gtid; i < total; i += (long)gridDim.x * blockDim.x) {
        const float* src; unsigned short* dst; unsigned short* lo_dst = nullptr; long off = i;
        bool tag_state = false;
        if (off < NX4)                   { src = x;    dst = xb; }
        else if ((off -= NX4) < NWIH4)   { src = wih;  dst = wihb; }
        else if ((off -= NWIH4) < NWHH4) { src = whh;  dst = wcomb; }
        else if ((off -= NWHH4) < NWREC4){ src = wrec; dst = wcomb + 4194304; lo_dst = wreclo; }
        else if ((off -= NWREC4) < NH4)  { src = h0;   dst = hst; lo_dst = hstlo; tag_state = true; }
        else { off -= NH4;  src = c0;  dst = cst; lo_dst = cstlo; tag_state = true; }
        float4 v = ((const float4*)src)[off];
        unsigned short hx = f2b(v.x), hy = f2b(v.y), hz = f2b(v.z), hw = f2b(v.w);
        // State carries gen=3 (both tag bits set) in the LSB of EVERY bf16;
        // lo (computed from the tagged hi) absorbs the hi tags exactly.
        if (tag_state) { hx |= 1u; hy |= 1u; hz |= 1u; hw |= 1u; }
        unsigned long long o = (unsigned long long)hx
            | ((unsigned long long)hy << 16)
            | ((unsigned long long)hz << 32)
            | ((unsigned long long)hw << 48);
        *(unsigned long long*)(dst + off * 4) = o;
        if (tag_state) *(unsigned long long*)(dst + 65536 + off * 4) = o;   // both slots
        if (lo_dst) {
            unsigned short lx = f2b(v.x - b2f(hx)), ly = f2b(v.y - b2f(hy));
            unsigned short lz = f2b(v.z - b2f(hz)), lw = f2b(v.w - b2f(hw));
            if (tag_state) { lx |= 1u; ly |= 1u; lz |= 1u; lw |= 1u; }
            unsigned long long l = (unsigned long long)lx
                | ((unsigned long long)ly << 16)
                | ((unsigned long long)lz << 32)
                | ((unsigned long long)lw << 48);
            *(unsigned long long*)(lo_dst + off * 4) = l;
            if (tag_state) *(unsigned long long*)(lo_dst + 65536 + off * 4) = l;
        }
    }
    if (gtid < 1024) flags[gtid] = 0;
}

// ---------------------------------------------------------------------------
// px GEMM: block = (t, 64-col slab), 4 waves, each wave one 16-col tile, M=64.
__global__ void __launch_bounds__(256) k_px(const unsigned short* __restrict__ xb,
                                            const unsigned short* __restrict__ wihb,
                                            const float* __restrict__ bias,
                                            unsigned short* __restrict__ px) {
    const int t = blockIdx.y;
    const int wv = threadIdx.x >> 6, lane = threadIdx.x & 63;
    const int col = lane & 15, quad = lane >> 4;
    const int n = blockIdx.x * 64 + wv * 16 + col;   // 0..4095 combined gate*H+j
    const float bn = bias[n];
    f4 acc[4];
#pragma unroll
    for (int mt = 0; mt < 4; ++mt) { acc[mt][0] = bn; acc[mt][1] = bn; acc[mt][2] = bn; acc[mt][3] = bn; }
    const unsigned short* bp = wihb + n * 512 + quad * 8;
#pragma unroll 4
    for (int kk = 0; kk < 16; ++kk) {
        short8 bf = *(const short8*)(bp + kk * 32);
#pragma unroll
        for (int mt = 0; mt < 4; ++mt) {
            const unsigned short* ap = xb + ((mt * 16 + col) * 188 + t) * 512 + kk * 32 + quad * 8;
            short8 af = *(const short8*)ap;
            acc[mt] = MFMA(af, bf, acc[mt]);
        }
    }
    const long pb = ((long)(t * 4 + (n >> 10)) * 1024 + (n & 1023)) * 64;
#pragma unroll
    for (int mt = 0; mt < 4; ++mt) {
        unsigned long long o = (unsigned long long)f2b(acc[mt][0])
            | ((unsigned long long)f2b(acc[mt][1]) << 16)
            | ((unsigned long long)f2b(acc[mt][2]) << 32)
            | ((unsigned long long)f2b(acc[mt][3]) << 48);
        *(unsigned long long*)(px + pb + mt * 16 + quad * 4) = o;
    }
}

// ---------------------------------------------------------------------------
// Persistent scan. cu = blockIdx: group g = cu>>6 (16 batch rows), cig = cu&63
// (16 hidden indices). 4 balanced waves, each owns K-slice kbase=wv*256 and
// computes: gates = px + h_hi@W_hh + h_lo@W_hh, peephole = c_hi@W_hi +
// c_hi@W_lo + c_lo@W_hi. 112 MFMA/wave. Sync: 2-bit per-dword in-band tags.
__global__ void __launch_bounds__(256, 1) k_scan(
    const unsigned short* __restrict__ wcomb, const unsigned short* __restrict__ wreclo,
    const float* __restrict__ c0, const int* __restrict__ lengths,
    const unsigned short* __restrict__ px, unsigned short* __restrict__ hst,
    unsigned short* __restrict__ cst, unsigned short* __restrict__ cstlo,
    unsigned short* __restrict__ hstlo, int* __restrict__ flags,
    float* __restrict__ out) {
    const int cu = blockIdx.x;
    const int g = cu >> 6, cig = cu & 63;
    const int jbase = cig * 16, b0 = g * 16;
    const int tid = threadIdx.x, wv = tid >> 6, lane = tid & 63;
    const int kbase = wv * 256;               // per-wave K-slice
    const int col = lane & 15, quad = lane >> 4;
    const int b_ = tid >> 4, j_ = tid & 15;

    __shared__ float pre[2][4][6][16][16];               // [slot][kq][tile][b][j]  48 KB
    __shared__ float c_loc[16][16];                      // fp32 local c
    __shared__ __align__(16) unsigned short epi[4][16][16];  // pack: h_hi,h_lo,c_hi,c_lo
    __shared__ __align__(16) unsigned short wlds[4][2][8][512]; // W_rec_lo slices 64 KB

    // One-time: W_hh + W_rec_hi -> regs; W_rec_lo -> LDS.
    short8 wg[4][8];   // i,f,g,o rows of W_hh
    short8 wh[2][8];   // ri_hi, rf_hi rows of W_rec hi
#pragma unroll
    for (int gate = 0; gate < 4; ++gate) {
        const unsigned short* src = wcomb + (long)(gate * 1024 + jbase + col) * 1024 + kbase + quad * 8;
#pragma unroll
        for (int kk = 0; kk < 8; ++kk) wg[gate][kk] = *(const short8*)(src + kk * 32);
    }
#pragma unroll
    for (int tl = 0; tl < 2; ++tl) {
        const unsigned short* sh = wcomb + (long)((4 + tl) * 1024 + jbase + col) * 1024 + kbase + quad * 8;
        const unsigned short* sl = wreclo + (long)(tl * 1024 + jbase + col) * 1024 + kbase + quad * 8;
#pragma unroll
        for (int kk = 0; kk < 8; ++kk) {
            wh[tl][kk] = *(const short8*)(sh + kk * 32);
            *(short8*)&wlds[wv][tl][kk][lane * 8] = *(const short8*)(sl + kk * 32);
        }
    }
    c_loc[b_][j_] = c0[(b0 + b_) * 1024 + jbase + j_];
    const int my_len = lengths[b0 + b_];
    float bl0 = (float)lane + 1.0f, bl1 = bl0 + 0.5f, bl2 = bl0 + 0.25f, bl3 = bl0 + 0.125f;
    __syncthreads();

    float* out_h = out;
    float* out_c = out + 12320768;

    for (int t = 0; t < T_N; ++t) {
        const int sl_r = (t + 1) & 1, sl_w = t & 1, ps = t & 1;
        // 2-bit generations: data written at step t carries gen (t>>1)&3;
        // prep data (the "t = -1 write") carries 3. Expected at step t:
        const int genr = (t == 0) ? 3 : (((t - 1) >> 1) & 3);
        const unsigned int pat = (unsigned int)(genr & 1)
                               | ((unsigned int)((genr >> 1) & 1) << 16);
        const int gw = (t >> 1) & 3;
        const unsigned int tb = (unsigned int)((j_ & 1) ? ((gw >> 1) & 1) : (gw & 1));

        // px loads (wave 0 only) are state-independent: in flight during gather.
        f4 pxv[4];
        if (wv == 0) {
#pragma unroll
            for (int tile = 0; tile < 4; ++tile)
                pxv[tile] = px_init(px, t, tile, jbase + col, b0 + quad * 4);
        }

        const int sbase = sl_r * 65536 + (b0 + col) * 1024 + kbase + quad * 8;

        // Validated gather: 32 x 16B (h_hi, h_lo, c_hi, c_lo); every DWORD
        // must carry gen_r's 2-bit pattern; retry until all fresh.
        short8 hb[8], hlb[8], cb[8], lb[8];
        for (;;) {
#pragma unroll
            for (int kk = 0; kk < 8; ++kk) LD16(hb[kk], hst + sbase + kk * 32);
#pragma unroll
            for (int kk = 0; kk < 8; ++kk) LD16(hlb[kk], hstlo + sbase + kk * 32);
#pragma unroll
            for (int kk = 0; kk < 8; ++kk) LD16(cb[kk], cst + sbase + kk * 32);
#pragma unroll
            for (int kk = 0; kk < 8; ++kk) LD16(lb[kk], cstlo + sbase + kk * 32);
            asm volatile("s_waitcnt vmcnt(0)" ::: "memory");
            __builtin_amdgcn_sched_barrier(0);
            unsigned int bad = 0;
#pragma unroll
            for (int kk = 0; kk < 8; ++kk) {
                bad |= tagxor(hb[kk], pat);
                bad |= tagxor(hlb[kk], pat);
                bad |= tagxor(cb[kk], pat);
                bad |= tagxor(lb[kk], pat);
            }
            if (__all((bad & 0x00010001u) == 0u)) break;
            BAL64();
        }

        f4 ag0, ag1, ag2, ag3;
        if (wv == 0) { ag0 = pxv[0]; ag1 = pxv[1]; ag2 = pxv[2]; ag3 = pxv[3]; }
        else {
            ag0[0] = 0.f; ag0[1] = 0.f; ag0[2] = 0.f; ag0[3] = 0.f;
            ag1 = ag0; ag2 = ag0; ag3 = ag0;
        }
        f4 ap0 = {0.f, 0.f, 0.f, 0.f}, ap1 = ap0, ap2 = ap0, ap3 = ap0, ap4 = ap0, ap5 = ap0;

#pragma unroll
        for (int kk = 0; kk < 8; ++kk) {
            short8 lw0 = *(const short8*)&wlds[wv][0][kk][lane * 8];
            short8 lw1 = *(const short8*)&wlds[wv][1][kk][lane * 8];
            ag0 = MFMA(hb[kk], wg[0][kk], ag0);
            ag1 = MFMA(hb[kk], wg[1][kk], ag1);
            ag2 = MFMA(hb[kk], wg[2][kk], ag2);
            ag3 = MFMA(hb[kk], wg[3][kk], ag3);
            ap0 = MFMA(cb[kk], wh[0][kk], ap0);   // c_hi @ ri_hi
            ap1 = MFMA(cb[kk], wh[1][kk], ap1);   // c_hi @ rf_hi
            ap2 = MFMA(cb[kk], lw0, ap2);         // c_hi @ ri_lo
            ap3 = MFMA(cb[kk], lw1, ap3);         // c_hi @ rf_lo
            ap4 = MFMA(lb[kk], wh[0][kk], ap4);   // c_lo @ ri_hi
            ap5 = MFMA(lb[kk], wh[1][kk], ap5);   // c_lo @ rf_hi
        }
#pragma unroll
        for (int kk = 0; kk < 8; ++kk) {          // h_lo compensation pass
            ag0 = MFMA(hlb[kk], wg[0][kk], ag0);
            ag1 = MFMA(hlb[kk], wg[1][kk], ag1);
            ag2 = MFMA(hlb[kk], wg[2][kk], ag2);
            ag3 = MFMA(hlb[kk], wg[3][kk], ag3);
        }
#pragma unroll
        for (int r = 0; r < 4; ++r) {
            pre[ps][wv][0][quad * 4 + r][col] = ag0[r];
            pre[ps][wv][1][quad * 4 + r][col] = ag1[r];
            pre[ps][wv][2][quad * 4 + r][col] = ag2[r];
            pre[ps][wv][3][quad * 4 + r][col] = ag3[r];
            pre[ps][wv][4][quad * 4 + r][col] = ap0[r] + ap2[r] + ap4[r];
            pre[ps][wv][5][quad * 4 + r][col] = ap1[r] + ap3[r] + ap5[r];
        }
        __syncthreads();   // bar1: pre[] complete

        float hn, cn;
        {
            float pi = 0.f, pf = 0.f, pg = 0.f, po = 0.f;
#pragma unroll
            for (int q = 0; q < 4; ++q) {
                pi += pre[ps][q][0][b_][j_] + pre[ps][q][4][b_][j_];
                pf += pre[ps][q][1][b_][j_] + pre[ps][q][5][b_][j_];
                pg += pre[ps][q][2][b_][j_];
                po += pre[ps][q][3][b_][j_];
            }
            const float cprev = c_loc[b_][j_];
            const float iv = sigf(pi), fv = sigf(pf), gv = tanh_(pg);
            cn = fv * cprev + iv * gv;
            float ov = sigf(po + cn);
            hn = ov * tanh_(cn);
            if (t >= my_len) { hn = 0.f; cn = 0.f; }
            c_loc[b_][j_] = cn;
            // hi tagged (its tag is absorbed exactly by lo, computed AFTER
            // tagging); lo tagged raw (~2^-17). Every bf16 carries its bit.
            unsigned short hhw = (unsigned short)((f2b(hn) & 0xFFFEu) | tb);
            unsigned short chw = (unsigned short)((f2b(cn) & 0xFFFEu) | tb);
            unsigned short hlw = (unsigned short)((f2b(hn - b2f(hhw)) & 0xFFFEu) | tb);
            unsigned short clw = (unsigned short)((f2b(cn - b2f(chw)) & 0xFFFEu) | tb);
            epi[0][b_][j_] = hhw;
            epi[1][b_][j_] = hlw;
            epi[2][b_][j_] = chw;
            epi[3][b_][j_] = clw;
        }
        __syncthreads();   // bar2: epi[] complete

        // Pack + publish: 128 chunks (4 arrays x 16 rows x 2), one 16B
        // coherent store each. No drain, no flag.
        if (tid < 128) {
            const int a = tid >> 5, cidx = tid & 31, row = cidx >> 1, q = cidx & 1;
            short8 v = *(const short8*)&epi[a][row][q * 8];
            unsigned short* arr = (a == 0) ? hst : (a == 1) ? hstlo : (a == 2) ? cst : cstlo;
            unsigned short* dstp = arr + sl_w * 65536 + (b0 + row) * 1024 + jbase + q * 8;
            ST16(dstp, v);
        }
        // Out stores: not consumed cross-CU, off the critical path.
        const long ob = (long)(b0 + b_) * 192512 + (long)t * 1024 + jbase + j_;
        out_h[ob] = hn;
        out_c[ob] = cn;
    }
    asm volatile("" :: "v"(bl0), "v"(bl1), "v"(bl2), "v"(bl3));   // keep ballast live
}

// ---------------------------------------------------------------------------
extern "C" void kernel_launch(void* const* d_in, const int* in_sizes, int n_in,
                              void* d_out, int out_size, void* d_ws, size_t ws_size,
                              hipStream_t stream) {
    const float* x    = (const float*)d_in[0];
    const float* h0   = (const float*)d_in[1];
    const float* c0   = (const float*)d_in[2];
    const float* wih  = (const float*)d_in[3];
    const float* whh  = (const float*)d_in[4];
    const float* wrec = (const float*)d_in[5];
    const float* bias = (const float*)d_in[6];
    const int* lengths = (const int*)d_in[7];

    char* ws = (char*)d_ws;
    unsigned short* px     = (unsigned short*)(ws + WS_PX);
    unsigned short* xb     = (unsigned short*)(ws + WS_XB);
    unsigned short* wihb   = (unsigned short*)(ws + WS_WIHB);
    unsigned short* wcomb  = (unsigned short*)(ws + WS_WCOMB);
    unsigned short* hst    = (unsigned short*)(ws + WS_HST);
    unsigned short* cst    = (unsigned short*)(ws + WS_CST);
    unsigned short* wreclo = (unsigned short*)(ws + WS_WRECLO);
    unsigned short* cstlo  = (unsigned short*)(ws + WS_CSTLO);
    unsigned short* hstlo  = (unsigned short*)(ws + WS_HSTLO);
    int* flags             = (int*)(ws + WS_FLAGS);
    float* out = (float*)d_out;

    hipLaunchKernelGGL(k_prep, dim3(2048), dim3(256), 0, stream,
                       x, h0, c0, wih, whh, wrec, xb, wihb, wcomb, hst, cst, wreclo,
                       cstlo, hstlo, flags);
    hipLaunchKernelGGL(k_px, dim3(64, 188), dim3(256), 0, stream, xb, wihb, bias, px);
    hipLaunchKernelGGL(k_scan, dim3(256), dim3(256), 0, stream,
                       wcomb, wreclo, c0, lengths, px, hst, cst, cstlo, hstlo, flags, out);
}

// Round 9
// 1446.303 us; speedup vs baseline: 1.5421x; 1.5421x over previous
//
#include <hip/hip_runtime.h>

// ---------------------------------------------------------------------------
// XiRNN (peephole LSTM) on MI355X.  B=64, T=188, I=512, H=R=1024.
//   k_prep : fp32->bf16 for x, W_ih, initial state only (slot 1). W_hh/W_rec
//            conversion moved INTO k_scan's one-time init (in-register).
//   k_px   : px[t][gate][j][b] GEMM. R16: 4x A-reuse — wave owns 64 n-cols
//            (4 tiles) x M=64; per kk: 4 B + 4 A loads -> 16 MFMAs.
//   k_scan : R11-exact protocol (best measured: 1140us): wave0 polls flags
//            with FMA ballast, LDS go_word release, batched sc0 sc1 gather,
//            per-CU flag post after vmcnt(0) drain.
//   Protocol history: R9 batched gather 1156 / R10 poll-flood FAIL 2050 /
//   R11 go_word 1140 / R12 balanced waves 1163 / R13-14 tag-sync accuracy
//   FAIL (false validation) / R15 tag-sync correct but 1750 (retry traffic
//   floods fabric, FETCH +190MB). Conclusion: ~6us/step is this family's
//   coherent-RT floor; R16 attacks the ~515us OUTSIDE k_scan instead.
// ---------------------------------------------------------------------------

#define T_N 188

// ws byte offsets (256-aligned). wcomb/wreclo regions retained but unused.
#define WS_PX     0UL           // ushort[188*4096*64]   = 98,566,144 B
#define WS_XB     98566144UL    // ushort[64*188*512]    = 12,320,768 B
#define WS_WIHB   110886912UL   // ushort[4096*512]      =  4,194,304 B
#define WS_WCOMB  115081216UL   // (unused)
#define WS_HST    127664128UL   // ushort[2][64][1024]   =    262,144 B
#define WS_CST    127926272UL   // ushort[2][64][1024]   =    262,144 B
#define WS_FLAGS  128188416UL   // int[1024]
#define WS_WRECLO 128192512UL   // (unused)
#define WS_CSTLO  132386816UL   // ushort[2][64][1024]   =    262,144 B

typedef __attribute__((ext_vector_type(8))) short short8;
typedef __attribute__((ext_vector_type(4))) float f4;

__device__ __forceinline__ float b2f(unsigned short u) {
    union { unsigned int i; float f; } v; v.i = ((unsigned int)u) << 16; return v.f;
}
__device__ __forceinline__ unsigned short f2b(float f) {
    unsigned int u = __float_as_uint(f);
    return (unsigned short)((u + 0x7FFFu + ((u >> 16) & 1u)) >> 16);
}
__device__ __forceinline__ float sigf(float x) { return 1.0f / (1.0f + __expf(-x)); }
__device__ __forceinline__ float tanh_(float x) {
    float e = __expf(2.0f * x); return 1.0f - 2.0f / (e + 1.0f);
}
#define MFMA(a, b, c) __builtin_amdgcn_mfma_f32_16x16x32_bf16((a), (b), (c), 0, 0, 0)

// 16B device-coherent load (bypass L1/L2). Result NOT tracked by compiler
// waitcnt logic — caller must s_waitcnt vmcnt(0) + sched_barrier(0) before use.
#define LD16(dst, addr) \
    asm volatile("global_load_dwordx4 %0, %1, off sc0 sc1" : "=&v"(dst) : "v"(addr))

// 16-FMA ballast burst (keeps SIMD active while waiting; R11-proven neutral+).
#define BALLAST(bal)                                                       \
    _Pragma("unroll")                                                      \
    for (int u_ = 0; u_ < 16; ++u_) bal = __builtin_fmaf(bal, 1.0000001f, 1e-7f)

__device__ __forceinline__ f4 px_init(const unsigned short* px, int t, int gate, int jg, int brow) {
    unsigned long long pv =
        *(const unsigned long long*)(px + ((long)(t * 4 + gate) * 1024 + jg) * 64 + brow);
    f4 r;
    r[0] = b2f((unsigned short)pv);
    r[1] = b2f((unsigned short)(pv >> 16));
    r[2] = b2f((unsigned short)(pv >> 32));
    r[3] = b2f((unsigned short)(pv >> 48));
    return r;
}

// ---------------------------------------------------------------------------
// R16 k_prep: only x->xb, wih->wihb, h0/c0->state slot 1 (+ c_lo). 2.10M
// float4 iterations (was 3.67M); W_hh/W_rec handled by k_scan init.
__global__ void k_prep(const float* __restrict__ x, const float* __restrict__ h0,
                       const float* __restrict__ c0, const float* __restrict__ wih,
                       unsigned short* __restrict__ xb, unsigned short* __restrict__ wihb,
                       unsigned short* __restrict__ hst, unsigned short* __restrict__ cst,
                       unsigned short* __restrict__ cstlo, int* __restrict__ flags) {
    const long NX4 = 1540096, NWIH4 = 524288, NH4 = 16384;
    const long total = NX4 + NWIH4 + NH4 + NH4;
    long gtid = (long)blockIdx.x * blockDim.x + threadIdx.x;
    for (long i = gtid; i < total; i += (long)gridDim.x * blockDim.x) {
        const float* src; unsigned short* dst; unsigned short* lo_dst = nullptr; long off = i;
        if (off < NX4)                  { src = x;   dst = xb; }
        else if ((off -= NX4) < NWIH4)  { src = wih; dst = wihb; }
        else if ((off -= NWIH4) < NH4)  { src = h0;  dst = hst + 65536; }     // state slot 1
        else { off -= NH4;                src = c0;  dst = cst + 65536; lo_dst = cstlo + 65536; }
        float4 v = ((const float4*)src)[off];
        unsigned short hx = f2b(v.x), hy = f2b(v.y), hz = f2b(v.z), hw = f2b(v.w);
        unsigned long long o = (unsigned long long)hx
            | ((unsigned long long)hy << 16)
            | ((unsigned long long)hz << 32)
            | ((unsigned long long)hw << 48);
        *(unsigned long long*)(dst + off * 4) = o;
        if (lo_dst) {
            unsigned long long l = (unsigned long long)f2b(v.x - b2f(hx))
                | ((unsigned long long)f2b(v.y - b2f(hy)) << 16)
                | ((unsigned long long)f2b(v.z - b2f(hz)) << 32)
                | ((unsigned long long)f2b(v.w - b2f(hw)) << 48);
            *(unsigned long long*)(lo_dst + off * 4) = l;
        }
    }
    if (gtid < 1024) flags[gtid] = 0;
}

// ---------------------------------------------------------------------------
// R16 k_px: block = (t, 256-col slab); 4 waves, each wave a 64-col slab
// (4 n-tiles) x M=64. Per kk: 4 B-loads + 4 A-loads -> 16 MFMAs (A reused
// across n-tiles, B across m-tiles): 0.5 loads/MFMA vs 1.25 before, and
// 3008 blocks vs 12032 (2.5x less L2/L3 traffic).
__global__ void __launch_bounds__(256) k_px(const unsigned short* __restrict__ xb,
                                            const unsigned short* __restrict__ wihb,
                                            const float* __restrict__ bias,
                                            unsigned short* __restrict__ px) {
    const int t = blockIdx.y;
    const int wv = threadIdx.x >> 6, lane = threadIdx.x & 63;
    const int col = lane & 15, quad = lane >> 4;
    const int nb = blockIdx.x * 256 + wv * 64;     // wave's 64-col slab
    f4 acc[4][4];                                  // [mt][nt]
#pragma unroll
    for (int nt = 0; nt < 4; ++nt) {
        const float bn = bias[nb + nt * 16 + col];
#pragma unroll
        for (int mt = 0; mt < 4; ++mt) {
            acc[mt][nt][0] = bn; acc[mt][nt][1] = bn; acc[mt][nt][2] = bn; acc[mt][nt][3] = bn;
        }
    }
#pragma unroll 4
    for (int kk = 0; kk < 16; ++kk) {
        short8 bf[4], af[4];
#pragma unroll
        for (int nt = 0; nt < 4; ++nt)
            bf[nt] = *(const short8*)(wihb + (nb + nt * 16 + col) * 512 + kk * 32 + quad * 8);
#pragma unroll
        for (int mt = 0; mt < 4; ++mt)
            af[mt] = *(const short8*)(xb + ((mt * 16 + col) * 188 + t) * 512 + kk * 32 + quad * 8);
#pragma unroll
        for (int mt = 0; mt < 4; ++mt)
#pragma unroll
            for (int nt = 0; nt < 4; ++nt)
                acc[mt][nt] = MFMA(af[mt], bf[nt], acc[mt][nt]);
    }
#pragma unroll
    for (int nt = 0; nt < 4; ++nt) {
        const int n = nb + nt * 16 + col;          // blocks never cross a gate (256 | 1024)
        const long pb = ((long)(t * 4 + (n >> 10)) * 1024 + (n & 1023)) * 64;
#pragma unroll
        for (int mt = 0; mt < 4; ++mt) {
            unsigned long long o = (unsigned long long)f2b(acc[mt][nt][0])
                | ((unsigned long long)f2b(acc[mt][nt][1]) << 16)
                | ((unsigned long long)f2b(acc[mt][nt][2]) << 32)
                | ((unsigned long long)f2b(acc[mt][nt][3]) << 48);
            *(unsigned long long*)(px + pb + mt * 16 + quad * 4) = o;
        }
    }
}

// ---------------------------------------------------------------------------
// Persistent scan — R11-exact protocol. cu = blockIdx: group g = cu>>6
// (16 batch rows), cig = cu&63 (16 hidden cols). 4 waves: kh = wv>>1, ts = wv&1.
//   ts0: tiles {i,f,g,o}, A = h, px seeded at kh==0.
//   ts1: tiles {ri,rf} compensated (c_hi@W_hi + c_hi@W_lo + c_lo@W_hi).
// R16 change: one-time weight init reads whh/wrec fp32 DIRECTLY, converting
// + hi/lo-splitting in-register (same f2b math as the old k_prep staging —
// bit-identical weights; removes the wcomb/wreclo staging pass entirely).
__global__ void __launch_bounds__(256, 1) k_scan(
    const float* __restrict__ whh, const float* __restrict__ wrec,
    const float* __restrict__ c0, const int* __restrict__ lengths,
    const unsigned short* __restrict__ px, unsigned short* __restrict__ hst,
    unsigned short* __restrict__ cst, unsigned short* __restrict__ cstlo,
    int* __restrict__ flags, float* __restrict__ out) {
    const int cu = blockIdx.x;
    const int g = cu >> 6, cig = cu & 63;
    const int jbase = cig * 16, b0 = g * 16;
    const int tid = threadIdx.x, wv = tid >> 6, lane = tid & 63;
    const int kh = wv >> 1, ts = wv & 1;
    const int kbase = kh * 512;
    const int col = lane & 15, quad = lane >> 4;

    __shared__ float pre[2][2][6][16][16];   // [slot][kh][tile][b][j]  24 KB
    __shared__ float c_loc[16][16];          // fp32 local c (never rounded)
    __shared__ int go_word;                  // LDS release hand-off

    // One-time: weights fp32 -> bf16 regs (convert in-register).
    short8 wf[4][16];
    if (ts == 0) {
        // tiles {i,f,g,o}: rows tile*1024 + jbase+col of W_hh.
#pragma unroll
        for (int tile = 0; tile < 4; ++tile) {
            const float* src = whh + (long)(tile * 1024 + jbase + col) * 1024 + kbase + quad * 8;
#pragma unroll
            for (int kk = 0; kk < 16; ++kk) {
                float4 a = *(const float4*)(src + kk * 32);
                float4 b = *(const float4*)(src + kk * 32 + 4);
                union { unsigned short u[8]; short8 s; } P;
                P.u[0] = f2b(a.x); P.u[1] = f2b(a.y); P.u[2] = f2b(a.z); P.u[3] = f2b(a.w);
                P.u[4] = f2b(b.x); P.u[5] = f2b(b.y); P.u[6] = f2b(b.z); P.u[7] = f2b(b.w);
                wf[tile][kk] = P.s;
            }
        }
    } else {
        // wf[0]=ri_hi, wf[1]=rf_hi, wf[2]=ri_lo, wf[3]=rf_lo from W_rec rows
        // tl*1024 + jbase+col; hi/lo computed in one pass.
#pragma unroll
        for (int tl = 0; tl < 2; ++tl) {
            const float* src = wrec + (long)(tl * 1024 + jbase + col) * 1024 + kbase + quad * 8;
#pragma unroll
            for (int kk = 0; kk < 16; ++kk) {
                float4 a = *(const float4*)(src + kk * 32);
                float4 b = *(const float4*)(src + kk * 32 + 4);
                float w[8] = {a.x, a.y, a.z, a.w, b.x, b.y, b.z, b.w};
                union { unsigned short u[8]; short8 s; } H, L;
#pragma unroll
                for (int e = 0; e < 8; ++e) {
                    unsigned short hi = f2b(w[e]);
                    H.u[e] = hi;
                    L.u[e] = f2b(w[e] - b2f(hi));
                }
                wf[tl][kk] = H.s;
                wf[2 + tl][kk] = L.s;
            }
        }
    }
    {
        int b = tid >> 4, j = tid & 15;
        c_loc[b][j] = c0[(b0 + b) * 1024 + jbase + j];
    }
    if (tid == 0) go_word = 0;
    const int my_len = lengths[b0 + (tid >> 4)];
    float bal = (float)lane + 1.0f;   // ballast accumulator (kept live)
    __syncthreads();

    float* out_h = out;
    float* out_c = out + 12320768;

    for (int t = 0; t < T_N; ++t) {
        const int sl_r = (t + 1) & 1, sl_w = t & 1, ps = t & 1;

        // px loads (ts0/kh0 only — gates 0..3) are state-independent: issue
        // before the wait so they're in flight while we poll.
        f4 pxv[4];
        if (ts == 0 && kh == 0) {
#pragma unroll
            for (int tile = 0; tile < 4; ++tile)
                pxv[tile] = px_init(px, t, tile, jbase + col, b0 + quad * 4);
        }

        if (t > 0) {
            if (wv == 0) {
                // Wave0 polls (lane i watches CU i of this group); ballast
                // between probes; releases block via LDS go_word.
                const int* fp = flags + g * 64 + lane;
                for (;;) {
                    int a = __hip_atomic_load(fp, __ATOMIC_RELAXED, __HIP_MEMORY_SCOPE_AGENT);
                    if (__all(a >= t)) break;
                    BALLAST(bal);
                }
                if (lane == 0)
                    __hip_atomic_store(&go_word, t, __ATOMIC_RELAXED, __HIP_MEMORY_SCOPE_WORKGROUP);
            } else {
                for (;;) {
                    int gw = __hip_atomic_load(&go_word, __ATOMIC_RELAXED, __HIP_MEMORY_SCOPE_WORKGROUP);
                    if (gw >= t) break;
                    BALLAST(bal);
                }
            }
            asm volatile("" ::: "memory");
        }

        const int sbase = sl_r * 65536 + (b0 + col) * 1024 + kbase + quad * 8;

        if (ts == 0) {
            const unsigned short* hp = hst + sbase;
            // Batch the entire h gather: 16 x 16B loads in flight at once.
            short8 hbuf[16];
#pragma unroll
            for (int kk = 0; kk < 16; ++kk) LD16(hbuf[kk], hp + kk * 32);
            f4 acc[4];
#pragma unroll
            for (int tile = 0; tile < 4; ++tile) {
                if (kh == 0) acc[tile] = pxv[tile];
                else { acc[tile][0] = 0.f; acc[tile][1] = 0.f; acc[tile][2] = 0.f; acc[tile][3] = 0.f; }
            }
            asm volatile("s_waitcnt vmcnt(0)" ::: "memory");
            __builtin_amdgcn_sched_barrier(0);
#pragma unroll
            for (int kk = 0; kk < 16; ++kk) {
                acc[0] = MFMA(hbuf[kk], wf[0][kk], acc[0]);
                acc[1] = MFMA(hbuf[kk], wf[1][kk], acc[1]);
                acc[2] = MFMA(hbuf[kk], wf[2][kk], acc[2]);
                acc[3] = MFMA(hbuf[kk], wf[3][kk], acc[3]);
            }
#pragma unroll
            for (int tile = 0; tile < 4; ++tile)
#pragma unroll
                for (int r = 0; r < 4; ++r) pre[ps][kh][tile][quad * 4 + r][col] = acc[tile][r];
        } else {
            const unsigned short* cph = cst + sbase;
            const unsigned short* cpl = cstlo + sbase;
            // Batch the entire c_hi + c_lo gather: 32 x 16B loads in flight.
            short8 chb[16], clb[16];
#pragma unroll
            for (int kk = 0; kk < 16; ++kk) LD16(chb[kk], cph + kk * 32);
#pragma unroll
            for (int kk = 0; kk < 16; ++kk) LD16(clb[kk], cpl + kk * 32);
            // 6 independent accumulator chains.
            f4 a0 = {0.f, 0.f, 0.f, 0.f}, a1 = a0, a2 = a0, a3 = a0, a4 = a0, a5 = a0;
            asm volatile("s_waitcnt vmcnt(0)" ::: "memory");
            __builtin_amdgcn_sched_barrier(0);
#pragma unroll
            for (int kk = 0; kk < 16; ++kk) {
                a0 = MFMA(chb[kk], wf[0][kk], a0);   // c_hi @ ri_hi
                a1 = MFMA(chb[kk], wf[1][kk], a1);   // c_hi @ rf_hi
                a2 = MFMA(chb[kk], wf[2][kk], a2);   // c_hi @ ri_lo
                a3 = MFMA(chb[kk], wf[3][kk], a3);   // c_hi @ rf_lo
                a4 = MFMA(clb[kk], wf[0][kk], a4);   // c_lo @ ri_hi
                a5 = MFMA(clb[kk], wf[1][kk], a5);   // c_lo @ rf_hi
            }
#pragma unroll
            for (int r = 0; r < 4; ++r) {
                pre[ps][kh][4][quad * 4 + r][col] = a0[r] + a2[r] + a4[r];
                pre[ps][kh][5][quad * 4 + r][col] = a1[r] + a3[r] + a5[r];
            }
        }
        __syncthreads();

        float hn, cn; long ob;
        {
            const int b = tid >> 4, j = tid & 15;
            float pi = pre[ps][0][0][b][j] + pre[ps][1][0][b][j] + pre[ps][0][4][b][j] + pre[ps][1][4][b][j];
            float pf = pre[ps][0][1][b][j] + pre[ps][1][1][b][j] + pre[ps][0][5][b][j] + pre[ps][1][5][b][j];
            float pg = pre[ps][0][2][b][j] + pre[ps][1][2][b][j];
            float po = pre[ps][0][3][b][j] + pre[ps][1][3][b][j];
            const float cprev = c_loc[b][j];
            const float iv = sigf(pi), fv = sigf(pf), gv = tanh_(pg);
            cn = fv * cprev + iv * gv;
            float ov = sigf(po + cn);
            hn = ov * tanh_(cn);
            if (t >= my_len) { hn = 0.f; cn = 0.f; }
            c_loc[b][j] = cn;
            ob = (long)(b0 + b) * 192512 + (long)t * 1024 + jbase + j;
            const int sidx = sl_w * 65536 + (b0 + b) * 1024 + jbase + j;
            unsigned short hb  = f2b(hn);
            unsigned short chb2 = f2b(cn);
            unsigned short clb2 = f2b(cn - b2f(chb2));
            __hip_atomic_store(&hst[sidx],  hb,   __ATOMIC_RELAXED, __HIP_MEMORY_SCOPE_AGENT);
            __hip_atomic_store(&cst[sidx],  chb2, __ATOMIC_RELAXED, __HIP_MEMORY_SCOPE_AGENT);
            __hip_atomic_store(&cstlo[sidx], clb2, __ATOMIC_RELAXED, __HIP_MEMORY_SCOPE_AGENT);
        }
        // Release: each wave drains its own state stores, barrier so all
        // waves' stores are complete, then ONE flag per CU.
        asm volatile("s_waitcnt vmcnt(0)" ::: "memory");
        __syncthreads();
        if (tid == 0)
            __hip_atomic_store(&flags[cu], t + 1, __ATOMIC_RELAXED, __HIP_MEMORY_SCOPE_AGENT);
        // Out stores AFTER the flag post: off the critical path.
        out_h[ob] = hn;
        out_c[ob] = cn;
    }
    asm volatile("" :: "v"(bal));   // keep ballast live
}

// ---------------------------------------------------------------------------
extern "C" void kernel_launch(void* const* d_in, const int* in_sizes, int n_in,
                              void* d_out, int out_size, void* d_ws, size_t ws_size,
                              hipStream_t stream) {
    const float* x    = (const float*)d_in[0];
    const float* h0   = (const float*)d_in[1];
    const float* c0   = (const float*)d_in[2];
    const float* wih  = (const float*)d_in[3];
    const float* whh  = (const float*)d_in[4];
    const float* wrec = (const float*)d_in[5];
    const float* bias = (const float*)d_in[6];
    const int* lengths = (const int*)d_in[7];

    char* ws = (char*)d_ws;
    unsigned short* px     = (unsigned short*)(ws + WS_PX);
    unsigned short* xb     = (unsigned short*)(ws + WS_XB);
    unsigned short* wihb   = (unsigned short*)(ws + WS_WIHB);
    unsigned short* hst    = (unsigned short*)(ws + WS_HST);
    unsigned short* cst    = (unsigned short*)(ws + WS_CST);
    unsigned short* cstlo  = (unsigned short*)(ws + WS_CSTLO);
    int* flags             = (int*)(ws + WS_FLAGS);
    float* out = (float*)d_out;

    hipLaunchKernelGGL(k_prep, dim3(2048), dim3(256), 0, stream,
                       x, h0, c0, wih, xb, wihb, hst, cst, cstlo, flags);
    hipLaunchKernelGGL(k_px, dim3(16, 188), dim3(256), 0, stream, xb, wihb, bias, px);
    hipLaunchKernelGGL(k_scan, dim3(256), dim3(256), 0, stream,
                       whh, wrec, c0, lengths, px, hst, cst, cstlo, flags, out);
}